// Round 14
// baseline (72.121 us; speedup 1.0000x reference)
//
#include <hip/hip_runtime.h>

#define B 8
#define C 512
#define D 2048     // spatial positions
#define L 2049     // D+1
#define NH 8
#define CH 64
#define NLT 32     // l-tiles of 64 in the fused pass

__device__ __forceinline__ float wave_sum(float v) {
  #pragma unroll
  for (int off = 32; off; off >>= 1) v += __shfl_down(v, off);
  return v;
}
__device__ __forceinline__ float wave_max(float v) {
  #pragma unroll
  for (int off = 32; off; off >>= 1) v = fmaxf(v, __shfl_down(v, off));
  return v;
}
// wave-uniform broadcast via v_readlane (SGPR result). Lane idx may be a
// wave-uniform runtime value (v_readlane_b32 takes SGPR lane).
__device__ __forceinline__ float lane_bcast(float v, int l) {
  return __uint_as_float(__builtin_amdgcn_readlane(__float_as_uint(v), l));
}

// ---- K1: mps[b,c] = mean_l x[b,c,l] + pos[c,0]. One block per (b,c) row.
//      Blocks with b==0 additionally copy pos_sh[c][l'] = pos[c][l'+1]
//      (shifted copy -> float4-aligned rows for the fused pass). ----
__global__ void __launch_bounds__(256) k_mean(const float* __restrict__ x,
                                              const float* __restrict__ pos,
                                              float* __restrict__ mps_g,
                                              float* __restrict__ pos_sh) {
  int row = blockIdx.x;  // b*C + c
  if (row < C) {         // b == 0: copy this c's shifted pos row
    const float* src = pos + (size_t)row * L + 1;
    float* dst = pos_sh + (size_t)row * D;
    #pragma unroll
    for (int i = 0; i < 8; ++i)
      dst[threadIdx.x + i * 256] = src[threadIdx.x + i * 256];
  }
  const float4* xr = reinterpret_cast<const float4*>(x + (size_t)row * D);
  float s = 0.f;
  #pragma unroll
  for (int i = 0; i < 2; ++i) {
    float4 v = xr[threadIdx.x + i * 256];
    s += (v.x + v.y) + (v.z + v.w);
  }
  __shared__ float red[4];
  s = wave_sum(s);
  if ((threadIdx.x & 63) == 0) red[threadIdx.x >> 6] = s;
  __syncthreads();
  if (threadIdx.x == 0)
    mps_g[row] = (red[0] + red[1] + red[2] + red[3]) * (1.0f / D)
               + pos[(size_t)(row & (C - 1)) * L];
}

// ---- K2: q0 -> u[b,h,:] -> logit0[b,h]. One block per (b,h). ----
__global__ void __launch_bounds__(256) k_qu(const float* __restrict__ wqkv,
                                            const float* __restrict__ bqkv,
                                            const float* __restrict__ mps_g,
                                            float* __restrict__ u,
                                            float* __restrict__ logit0) {
  int bh = blockIdx.x, b = bh >> 3, h = bh & 7;
  int tid = threadIdx.x, wid = tid >> 6, lane = tid & 63;
  __shared__ float mps[C];
  __shared__ float q0s[CH];
  __shared__ float us[C];
  __shared__ float red[4];
  for (int c = tid; c < C; c += 256) mps[c] = mps_g[b * C + c];
  __syncthreads();
  for (int j = wid; j < CH; j += 4) {
    const float* wr = wqkv + (size_t)(h * CH + j) * C;
    float acc = 0.f;
    #pragma unroll
    for (int k = 0; k < 8; ++k) acc += wr[lane + k * 64] * mps[lane + k * 64];
    acc = wave_sum(acc);
    if (lane == 0) q0s[j] = acc + bqkv[h * CH + j];
  }
  __syncthreads();
  float a0 = 0.f, a1 = 0.f;
  #pragma unroll 4
  for (int j = 0; j < CH; ++j) {
    float qv = q0s[j];
    const float* wkr = wqkv + (size_t)(C + h * CH + j) * C;
    a0 += qv * wkr[tid];
    a1 += qv * wkr[tid + 256];
  }
  a0 *= 0.125f; a1 *= 0.125f;   // scale^2 = 1/sqrt(64)
  us[tid] = a0; us[tid + 256] = a1;
  u[(size_t)bh * C + tid] = a0;
  u[(size_t)bh * C + tid + 256] = a1;
  __syncthreads();
  float p = us[tid] * mps[tid] + us[tid + 256] * mps[tid + 256];
  p = wave_sum(p);
  if (lane == 0) red[wid] = p;
  __syncthreads();
  if (tid == 0) logit0[bh] = red[0] + red[1] + red[2] + red[3];
}

// ---- K3: fused logits + local softmax + xbar partials, x in REGISTERS.
// grid (NLT, B) = 256 blocks, 512 thr, 1 block/CU.
// Lane (ls=lane&15, cs=lane>>4); wave w owns c-rows [w*64, w*64+64).
// Phase A: 16 iters, lane loads float4 x + float4 pos_sh for row cg+4k+cs,
//   keeps xf in v[16] (64 VGPR, live across softmax), logits via LDS u-bcast.
// Softmax: wave<->head local softmax over the 64 l's; mpart/spart partials.
// Phase B: xbar partials from v[] (zero loads), 16-lane shfl_xor row-dots. ----
__global__ void __launch_bounds__(512, 2) k_fused(
    const float* __restrict__ x, const float* __restrict__ pos_sh,
    const float* __restrict__ u_g,
    float* __restrict__ xpart, float* __restrict__ mpart, float* __restrict__ spart) {
  __shared__ float us[NH][C];         // 16 KB
  __shared__ float rlds[8][NH][64];   // 16 KB
  __shared__ float e_t[64][NH + 1];   // 2.3 KB (stride 9: conflict-free)
  int lt = blockIdx.x, b = blockIdx.y;
  int tid = threadIdx.x, w = tid >> 6, lane = tid & 63;
  int ls = lane & 15, cs = lane >> 4;
  int cg = w * 64;

  #pragma unroll
  for (int h = 0; h < NH; ++h) us[h][tid] = u_g[(size_t)(b * NH + h) * C + tid];
  __syncthreads();

  const float4* x4 = reinterpret_cast<const float4*>(x);
  const float4* p4 = reinterpret_cast<const float4*>(pos_sh);
  const int fbase = lt * 16 + ls;      // float4 index within a row

  float4 v[16];
  float4 acc[NH];
  #pragma unroll
  for (int h = 0; h < NH; ++h) acc[h] = make_float4(0.f, 0.f, 0.f, 0.f);
  #pragma unroll
  for (int k = 0; k < 16; ++k) {
    int row = cg + 4 * k + cs;
    float4 xv = x4[((size_t)(b * C) + row) * (D / 4) + fbase];
    float4 pv = p4[(size_t)row * (D / 4) + fbase];
    xv.x += pv.x; xv.y += pv.y; xv.z += pv.z; xv.w += pv.w;
    v[k] = xv;
    #pragma unroll
    for (int h = 0; h < NH; ++h) {
      float uu = us[h][row];           // 4-address LDS broadcast
      acc[h].x += uu * xv.x; acc[h].y += uu * xv.y;
      acc[h].z += uu * xv.z; acc[h].w += uu * xv.w;
    }
  }
  // reduce logits over the 4 cs-groups (c within wave)
  #pragma unroll
  for (int h = 0; h < NH; ++h) {
    acc[h].x += __shfl_xor(acc[h].x, 16); acc[h].y += __shfl_xor(acc[h].y, 16);
    acc[h].z += __shfl_xor(acc[h].z, 16); acc[h].w += __shfl_xor(acc[h].w, 16);
    acc[h].x += __shfl_xor(acc[h].x, 32); acc[h].y += __shfl_xor(acc[h].y, 32);
    acc[h].z += __shfl_xor(acc[h].z, 32); acc[h].w += __shfl_xor(acc[h].w, 32);
  }
  if (cs == 0) {
    #pragma unroll
    for (int h = 0; h < NH; ++h)
      *reinterpret_cast<float4*>(&rlds[w][h][ls * 4]) = acc[h];
  }
  __syncthreads();

  {  // wave w finishes head h = w: cross-wave reduce + local softmax
    int h = w;
    float lg = 0.f;
    #pragma unroll
    for (int w2 = 0; w2 < 8; ++w2) lg += rlds[w2][h][lane];
    float m = lane_bcast(wave_max(lg), 0);
    float e = __expf(lg - m);
    float s = wave_sum(e);
    e_t[lane][h] = e;
    if (lane == 0) {
      mpart[(b * NH + h) * NLT + lt] = m;
      spart[(b * NH + h) * NLT + lt] = s;
    }
  }
  __syncthreads();

  // Phase B: row-dots against e from registers; 16-lane xor-reduce.
  #pragma unroll
  for (int h = 0; h < NH; ++h) {
    float e0 = e_t[ls * 4 + 0][h], e1 = e_t[ls * 4 + 1][h];
    float e2 = e_t[ls * 4 + 2][h], e3 = e_t[ls * 4 + 3][h];
    #pragma unroll
    for (int k = 0; k < 16; ++k) {
      float s = e0 * v[k].x + e1 * v[k].y + e2 * v[k].z + e3 * v[k].w;
      s += __shfl_xor(s, 1);
      s += __shfl_xor(s, 2);
      s += __shfl_xor(s, 4);
      s += __shfl_xor(s, 8);
      if (ls == 0)
        xpart[(((size_t)b * NLT + lt) * NH + h) * C + cg + 4 * k + cs] = s;
    }
  }
}

// ---- K4: combine 32 tile-partials + l=0 term, normalize -> xbar row (LDS),
//          then a0 slice for this head. Block = (b,h), 64 blocks. ----
__global__ void __launch_bounds__(512) k_a0(
    const float* __restrict__ xpart, const float* __restrict__ mpart,
    const float* __restrict__ spart, const float* __restrict__ logit0,
    const float* __restrict__ mps_g,
    const float* __restrict__ wqkv, const float* __restrict__ bqkv,
    float* __restrict__ a0v) {
  int bh = blockIdx.x, b = bh >> 3, h = bh & 7;
  int tid = threadIdx.x, wid = tid >> 6, lane = tid & 63;
  __shared__ float row[C];
  float lg0 = logit0[bh];
  // per-wave (redundant) combine factors in lane registers
  float mt = (lane < NLT) ? mpart[bh * NLT + lane] : -3.0e38f;
  float M = fmaxf(lane_bcast(wave_max(mt), 0), lg0);
  float rr = (lane < NLT) ? __expf(mt - M) : 0.f;
  float st = (lane < NLT) ? spart[bh * NLT + lane] * rr : 0.f;
  float S = lane_bcast(wave_sum(st), 0) + __expf(lg0 - M);
  float Sinv = 1.0f / S;
  // xbar[c=tid]
  float acc = 0.f;
  #pragma unroll 8
  for (int t = 0; t < NLT; ++t)
    acc += xpart[(((size_t)b * NLT + t) * NH + h) * C + tid] * lane_bcast(rr, t);
  acc = (acc + __expf(lg0 - M) * mps_g[b * C + tid]) * Sinv;
  row[tid] = acc;
  __syncthreads();
  // a0[b, h*64+j]: xbar row cached in 8 regs, wave wid handles 8 outputs
  float xr[8];
  #pragma unroll
  for (int k = 0; k < 8; ++k) xr[k] = row[k * 64 + lane];
  #pragma unroll 2
  for (int j = 0; j < 8; ++j) {
    int o = h * CH + wid * 8 + j;
    const float* wr = wqkv + (size_t)(2 * C + o) * C;
    float d = 0.f;
    #pragma unroll
    for (int k = 0; k < 8; ++k) d += wr[k * 64 + lane] * xr[k];
    d = wave_sum(d);
    if (lane == 0) a0v[b * C + o] = d + bqkv[2 * C + o];
  }
}

// ---- K5: out[b,o] = W_c[o,:] . a0[b,:] + b_c[o]. Block = (b, 64-o chunk). ----
__global__ void __launch_bounds__(512) k_out(const float* __restrict__ wc,
                                             const float* __restrict__ bc,
                                             const float* __restrict__ a0v,
                                             float* __restrict__ out) {
  int bid = blockIdx.x, b = bid >> 3, og = (bid & 7) * 64;
  int tid = threadIdx.x, wid = tid >> 6, lane = tid & 63;
  __shared__ float row[C];
  row[tid] = a0v[b * C + tid];
  __syncthreads();
  float ar[8];
  #pragma unroll
  for (int k = 0; k < 8; ++k) ar[k] = row[k * 64 + lane];
  #pragma unroll 2
  for (int j = 0; j < 8; ++j) {
    int o = og + wid * 8 + j;
    const float* wr = wc + (size_t)o * C;
    float d = 0.f;
    #pragma unroll
    for (int k = 0; k < 8; ++k) d += wr[k * 64 + lane] * ar[k];
    d = wave_sum(d);
    if (lane == 0) out[b * C + o] = d + bc[o];
  }
}

extern "C" void kernel_launch(void* const* d_in, const int* in_sizes, int n_in,
                              void* d_out, int out_size, void* d_ws, size_t ws_size,
                              hipStream_t stream) {
  const float* x    = (const float*)d_in[0];
  const float* pos  = (const float*)d_in[1];
  const float* wqkv = (const float*)d_in[2];
  const float* bqkv = (const float*)d_in[3];
  const float* wc   = (const float*)d_in[4];
  const float* bc   = (const float*)d_in[5];
  float* out = (float*)d_out;
  float* ws  = (float*)d_ws;

  float* mps_g  = ws;               // 4096
  float* u      = ws + 4096;        // 32768
  float* logit0 = ws + 36864;       // 64
  float* mpart  = ws + 36928;       // 2048
  float* spart  = ws + 38976;       // 2048
  float* a0v    = ws + 41024;       // 4096
  float* pos_sh = ws + 45120;       // 512*2048 = 1048576 (4 MB)
  float* xpart  = ws + 1093696;     // 8*32*8*512 = 1048576 (4 MB)

  hipLaunchKernelGGL(k_mean,  dim3(B * C),  dim3(256), 0, stream, x, pos, mps_g, pos_sh);
  hipLaunchKernelGGL(k_qu,    dim3(B * NH), dim3(256), 0, stream, wqkv, bqkv, mps_g, u, logit0);
  hipLaunchKernelGGL(k_fused, dim3(NLT, B), dim3(512), 0, stream, x, pos_sh, u, xpart, mpart, spart);
  hipLaunchKernelGGL(k_a0,    dim3(B * NH), dim3(512), 0, stream, xpart, mpart, spart, logit0,
                     mps_g, wqkv, bqkv, a0v);
  hipLaunchKernelGGL(k_out,   dim3(B * NH), dim3(512), 0, stream, wc, bc, a0v, out);
}